// Round 4
// baseline (293.194 us; speedup 1.0000x reference)
//
#include <hip/hip_runtime.h>
#include <math.h>

#define NG 16
#define DIM 64
#define LOG_2PI 1.8378770664093453f
#define WPB 4   // waves per block

// Persistent-wave GMM loss. One wave per row, grid-strided, with an explicit
// 2-row register ping-pong pipeline: row n+1's loads are issued before row n
// is consumed, so each wave always has ~2.3 KiB of loads in flight while its
// serial tail (shuffle reductions + transcendentals) executes.
// Lane layout (as R1): q = lane>>4 selects 1 of 4 gaussians per pass,
// dpart = lane&15 selects the 4-dim chunk; 4 passes cover 16 gaussians.

struct Row {
    float4 m0, m1, m2, m3;   // means: 4 passes x float4
    float4 v0, v1, v2, v3;   // covs
    float4 t;                // target chunk for this lane's dims
    float  w0, w1, w2, w3;   // weights for gaussians q, 4+q, 8+q, 12+q
};

__device__ __forceinline__ void load_row(const float* __restrict__ means,
                                         const float* __restrict__ covs,
                                         const float* __restrict__ targets,
                                         const float* __restrict__ weights,
                                         size_t b, int lane, int dpart, int q,
                                         Row& r)
{
    const float4* m4 = (const float4*)(means + b * (size_t)(NG * DIM));
    const float4* v4 = (const float4*)(covs  + b * (size_t)(NG * DIM));
    r.m0 = m4[lane];        r.v0 = v4[lane];
    r.m1 = m4[64  + lane];  r.v1 = v4[64  + lane];
    r.m2 = m4[128 + lane];  r.v2 = v4[128 + lane];
    r.m3 = m4[192 + lane];  r.v3 = v4[192 + lane];
    r.t  = ((const float4*)(targets + b * DIM))[dpart];
    const float* wrow = weights + b * NG;
    r.w0 = wrow[q];
    r.w1 = wrow[4  + q];
    r.w2 = wrow[8  + q];
    r.w3 = wrow[12 + q];
}

__device__ __forceinline__ float part(const float4 m, const float4 v, const float4 t)
{
    float dx = t.x - m.x;
    float p  = dx * dx * __builtin_amdgcn_rcpf(v.x);
    dx = t.y - m.y; p += dx * dx * __builtin_amdgcn_rcpf(v.y);
    dx = t.z - m.z; p += dx * dx * __builtin_amdgcn_rcpf(v.z);
    dx = t.w - m.w; p += dx * dx * __builtin_amdgcn_rcpf(v.w);
    // sum of 4 logs == log of product; product in [0.0625, 5.06] -> exact-safe
    p += __logf(v.x * v.y * v.z * v.w);
    return p;
}

__device__ __forceinline__ void process_row(const Row& r,
                                            float* __restrict__ out,
                                            size_t b, int lane)
{
    float s0 = part(r.m0, r.v0, r.t);
    float s1 = part(r.m1, r.v1, r.t);
    float s2 = part(r.m2, r.v2, r.t);
    float s3 = part(r.m3, r.v3, r.t);
    // sum (quad + logdet) across the 16 lanes of each gaussian's group;
    // 4 independent chains interleaved per stage so DS latency overlaps
#pragma unroll
    for (int st = 1; st < 16; st <<= 1) {
        s0 += __shfl_xor(s0, st);
        s1 += __shfl_xor(s1, st);
        s2 += __shfl_xor(s2, st);
        s3 += __shfl_xor(s3, st);
    }
    const float c = -0.5f * (DIM * LOG_2PI);
    float l0 = fminf(fmaxf(c - 0.5f * s0, -100.0f), 0.0f) + __logf(r.w0);
    float l1 = fminf(fmaxf(c - 0.5f * s1, -100.0f), 0.0f) + __logf(r.w1);
    float l2 = fminf(fmaxf(c - 0.5f * s2, -100.0f), 0.0f) + __logf(r.w2);
    float l3 = fminf(fmaxf(c - 0.5f * s3, -100.0f), 0.0f) + __logf(r.w3);

    // logsumexp over 16 gaussians: 4 in-register + cross-group (xor 16, 32)
    float M = fmaxf(fmaxf(l0, l1), fmaxf(l2, l3));
    M = fmaxf(M, __shfl_xor(M, 16));
    M = fmaxf(M, __shfl_xor(M, 32));
    float e = __expf(l0 - M) + __expf(l1 - M) + __expf(l2 - M) + __expf(l3 - M);
    e += __shfl_xor(e, 16);
    e += __shfl_xor(e, 32);

    if (lane == 0) out[b] = -(M + __logf(e));
}

__global__ __launch_bounds__(256, 4) void gmm_loss_kernel(
    const float* __restrict__ means,
    const float* __restrict__ covs,
    const float* __restrict__ weights,
    const float* __restrict__ targets,
    float* __restrict__ out, int B, int stride)
{
    const int wave_id = blockIdx.x * WPB + (threadIdx.x >> 6);
    const int lane  = threadIdx.x & 63;
    const int q     = lane >> 4;
    const int dpart = lane & 15;

    size_t b = (size_t)wave_id;
    if (b >= (size_t)B) return;

    Row A, C;
    load_row(means, covs, targets, weights, b, lane, dpart, q, A);
    size_t bn = b + stride;

    while (bn < (size_t)B) {
        load_row(means, covs, targets, weights, bn, lane, dpart, q, C);
        process_row(A, out, b, lane);
        b = bn; bn += stride;
        if (bn < (size_t)B) {
            load_row(means, covs, targets, weights, bn, lane, dpart, q, A);
            process_row(C, out, b, lane);
            b = bn; bn += stride;
        } else {
            process_row(C, out, b, lane);
            return;
        }
    }
    process_row(A, out, b, lane);
}

extern "C" void kernel_launch(void* const* d_in, const int* in_sizes, int n_in,
                              void* d_out, int out_size, void* d_ws, size_t ws_size,
                              hipStream_t stream) {
    const float* means   = (const float*)d_in[0];
    const float* covs    = (const float*)d_in[1];
    const float* weights = (const float*)d_in[2];
    const float* targets = (const float*)d_in[3];
    float* out = (float*)d_out;

    const int B = in_sizes[0] / (NG * DIM);   // 32768
    // 1024 blocks = 4 blocks/CU on 256 CUs; 4096 persistent waves, 8 rows each
    int blocks = 1024;
    if (blocks * WPB > B) blocks = (B + WPB - 1) / WPB;  // tiny-B safety
    const int stride = blocks * WPB;
    gmm_loss_kernel<<<blocks, 256, 0, stream>>>(means, covs, weights, targets,
                                                out, B, stride);
}

// Round 5
// 282.383 us; speedup vs baseline: 1.0383x; 1.0383x over previous
//
#include <hip/hip_runtime.h>
#include <math.h>

#define NG 16
#define DIM 64
#define LOG_2PI 1.8378770664093453f
#define WPB 4   // waves per block

// Persistent-wave GMM loss, 2-row register ping-pong pipeline (R4 structure).
// R4 post-mortem: the pipeline worked (2.5 TB/s) but the register allocator
// targeted 8 waves/EU, capped at 64 VGPRs, and spilled the ping-pong Row
// buffers to scratch (+80 MB writes, +77 MB re-reads per dispatch).
// Fix: amdgpu_waves_per_eu(2,4) caps the occupancy target at 4 waves/EU so
// the ~100 live VGPRs fit in registers (budget 128-256, no spill).

struct Row {
    float4 m0, m1, m2, m3;   // means: 4 passes x float4
    float4 v0, v1, v2, v3;   // covs
    float4 t;                // target chunk for this lane's dims
    float  w0, w1, w2, w3;   // weights for gaussians q, 4+q, 8+q, 12+q
};

__device__ __forceinline__ void load_row(const float* __restrict__ means,
                                         const float* __restrict__ covs,
                                         const float* __restrict__ targets,
                                         const float* __restrict__ weights,
                                         size_t b, int lane, int dpart, int q,
                                         Row& r)
{
    const float4* m4 = (const float4*)(means + b * (size_t)(NG * DIM));
    const float4* v4 = (const float4*)(covs  + b * (size_t)(NG * DIM));
    r.m0 = m4[lane];        r.v0 = v4[lane];
    r.m1 = m4[64  + lane];  r.v1 = v4[64  + lane];
    r.m2 = m4[128 + lane];  r.v2 = v4[128 + lane];
    r.m3 = m4[192 + lane];  r.v3 = v4[192 + lane];
    r.t  = ((const float4*)(targets + b * DIM))[dpart];
    const float* wrow = weights + b * NG;
    r.w0 = wrow[q];
    r.w1 = wrow[4  + q];
    r.w2 = wrow[8  + q];
    r.w3 = wrow[12 + q];
}

__device__ __forceinline__ float part(const float4 m, const float4 v, const float4 t)
{
    float dx = t.x - m.x;
    float p  = dx * dx * __builtin_amdgcn_rcpf(v.x);
    dx = t.y - m.y; p += dx * dx * __builtin_amdgcn_rcpf(v.y);
    dx = t.z - m.z; p += dx * dx * __builtin_amdgcn_rcpf(v.z);
    dx = t.w - m.w; p += dx * dx * __builtin_amdgcn_rcpf(v.w);
    // sum of 4 logs == log of product; product in [0.0625, 5.06] -> exact-safe
    p += __logf(v.x * v.y * v.z * v.w);
    return p;
}

__device__ __forceinline__ void process_row(const Row& r,
                                            float* __restrict__ out,
                                            size_t b, int lane)
{
    float s0 = part(r.m0, r.v0, r.t);
    float s1 = part(r.m1, r.v1, r.t);
    float s2 = part(r.m2, r.v2, r.t);
    float s3 = part(r.m3, r.v3, r.t);
    // sum (quad + logdet) across the 16 lanes of each gaussian's group;
    // 4 independent chains interleaved per stage so DS latency overlaps
#pragma unroll
    for (int st = 1; st < 16; st <<= 1) {
        s0 += __shfl_xor(s0, st);
        s1 += __shfl_xor(s1, st);
        s2 += __shfl_xor(s2, st);
        s3 += __shfl_xor(s3, st);
    }
    const float c = -0.5f * (DIM * LOG_2PI);
    float l0 = fminf(fmaxf(c - 0.5f * s0, -100.0f), 0.0f) + __logf(r.w0);
    float l1 = fminf(fmaxf(c - 0.5f * s1, -100.0f), 0.0f) + __logf(r.w1);
    float l2 = fminf(fmaxf(c - 0.5f * s2, -100.0f), 0.0f) + __logf(r.w2);
    float l3 = fminf(fmaxf(c - 0.5f * s3, -100.0f), 0.0f) + __logf(r.w3);

    // logsumexp over 16 gaussians: 4 in-register + cross-group (xor 16, 32)
    float M = fmaxf(fmaxf(l0, l1), fmaxf(l2, l3));
    M = fmaxf(M, __shfl_xor(M, 16));
    M = fmaxf(M, __shfl_xor(M, 32));
    float e = __expf(l0 - M) + __expf(l1 - M) + __expf(l2 - M) + __expf(l3 - M);
    e += __shfl_xor(e, 16);
    e += __shfl_xor(e, 32);

    if (lane == 0) out[b] = -(M + __logf(e));
}

__global__ __launch_bounds__(256)
__attribute__((amdgpu_waves_per_eu(2, 4)))
void gmm_loss_kernel(
    const float* __restrict__ means,
    const float* __restrict__ covs,
    const float* __restrict__ weights,
    const float* __restrict__ targets,
    float* __restrict__ out, int B, int stride)
{
    const int wave_id = blockIdx.x * WPB + (threadIdx.x >> 6);
    const int lane  = threadIdx.x & 63;
    const int q     = lane >> 4;
    const int dpart = lane & 15;

    size_t b = (size_t)wave_id;
    if (b >= (size_t)B) return;

    Row A, C;
    load_row(means, covs, targets, weights, b, lane, dpart, q, A);
    size_t bn = b + stride;

    while (bn < (size_t)B) {
        load_row(means, covs, targets, weights, bn, lane, dpart, q, C);
        process_row(A, out, b, lane);
        b = bn; bn += stride;
        if (bn < (size_t)B) {
            load_row(means, covs, targets, weights, bn, lane, dpart, q, A);
            process_row(C, out, b, lane);
            b = bn; bn += stride;
        } else {
            process_row(C, out, b, lane);
            return;
        }
    }
    process_row(A, out, b, lane);
}

extern "C" void kernel_launch(void* const* d_in, const int* in_sizes, int n_in,
                              void* d_out, int out_size, void* d_ws, size_t ws_size,
                              hipStream_t stream) {
    const float* means   = (const float*)d_in[0];
    const float* covs    = (const float*)d_in[1];
    const float* weights = (const float*)d_in[2];
    const float* targets = (const float*)d_in[3];
    float* out = (float*)d_out;

    const int B = in_sizes[0] / (NG * DIM);   // 32768
    // 1024 blocks = 4 blocks/CU if VGPR<=128; 4096 persistent waves, 8 rows each
    int blocks = 1024;
    if (blocks * WPB > B) blocks = (B + WPB - 1) / WPB;  // tiny-B safety
    const int stride = blocks * WPB;
    gmm_loss_kernel<<<blocks, 256, 0, stream>>>(means, covs, weights, targets,
                                                out, B, stride);
}